// Round 3
// baseline (146.315 us; speedup 1.0000x reference)
//
#include <hip/hip_runtime.h>
#include <math.h>

#define NUM_CLASSES 10
#define GRID_H 80
#define GRID_W 80
#define NCELLS (GRID_H * GRID_W)
#define NBOX 64
#define SEG (1024 * 1024)   // Hs*Ws per (batch[,channel])
#define XBLK 64             // x-blocks per streaming slice
#define TPB 256

// ws layout (doubles):
//  0..7    obj_sum[b]
//  8..15   box_sum[b]
// 16..23   cls_sum[b]
// 24..31   npos[b]
// 32..39   da_sum[b]
// 40..47   da_cnt[b]
// 48..71   rm_focal[b*3+c]
// 72..95   rm_inter[ch]
// 96..119  rm_probsum[ch]
// 120..143 rm_rtsum[ch]
// 144..167 rm_cnt[ch]
#define WS_DOUBLES 168

__device__ __forceinline__ void reduce_atomic(double v, double* gdst, double* smem) {
    #pragma unroll
    for (int off = 32; off > 0; off >>= 1) v += __shfl_down(v, off, 64);
    int lane = threadIdx.x & 63, wid = threadIdx.x >> 6;
    __syncthreads();               // protect smem reuse across successive calls
    if (lane == 0) smem[wid] = v;
    __syncthreads();
    if (threadIdx.x == 0) {
        double s = 0.0;
        int nw = blockDim.x >> 6;
        for (int i = 0; i < nw; i++) s += smem[i];
        atomicAdd(gdst, s);
    }
}

// t assumed in {0,1} for the -log(pt) identity (mask values are 0/1/255).
__device__ __forceinline__ void elem_rm(float x, int m,
        float& focal, float& inter, float& ps, float& ts, float& cnt) {
    const float vf = (m != 255) ? 1.0f : 0.0f;
    const float t  = (m != 255) ? (float)m : 0.0f;
    const float e  = __expf(-fabsf(x));
    const float sp = __builtin_amdgcn_rcpf(1.0f + e);
    const float sn = e * sp;
    const bool xp = (x >= 0.0f);
    const bool tp = (t > 0.5f);
    const float prob = xp ? sp : sn;          // sigmoid(x)
    const float pt   = (xp == tp) ? sp : sn;  // prob*t + (1-prob)*(1-t)
    const float om   = (xp == tp) ? sn : sp;  // 1 - pt
    const float bce  = -__logf(pt);
    focal += vf * (om * om * bce);
    inter += prob * t;                        // t==0 when invalid
    ps    += vf * prob;
    ts    += t;
    cnt   += vf;
}

__device__ __forceinline__ void elem_da(float x, int m, float& s, float& cnt) {
    const float vf = (m != 255) ? 1.0f : 0.0f;
    const float t  = (m != 255) ? (float)m : 0.0f;
    const float e  = __expf(-fabsf(x));
    const float sp = __builtin_amdgcn_rcpf(1.0f + e);
    const float sn = e * sp;
    const float pt = ((x >= 0.0f) == (t > 0.5f)) ? sp : sn;
    s   += vf * (-__logf(pt));
    cnt += vf;
}

// y==0: det; y in [1,25): rm channel y-1; y in [25,33): da batch y-25
__global__ __launch_bounds__(TPB) void fused_kernel(
        const float* __restrict__ det_logits,
        const float* __restrict__ det_yolo,
        const float* __restrict__ da_logits,
        const int*   __restrict__ da_mask,
        const float* __restrict__ rm_logits,
        const int*   __restrict__ rm_mask,
        double* __restrict__ acc) {
    __shared__ float gt[NBOX * 5];
    __shared__ double smem[8];
    const int y = blockIdx.y;
    const int tid = threadIdx.x;

    if (y == 0) {
        // ---------------- det (OD): 25 x-blocks x 8 batches via x = b*25+cb
        if (blockIdx.x >= 25) return;
        for (int b = 0; b < 8; b++) {
            const float* g = det_yolo + (size_t)b * NBOX * 5;
            __syncthreads();
            for (int i = tid; i < NBOX * 5; i += TPB) gt[i] = g[i];
            __syncthreads();
            const int cell = blockIdx.x * TPB + tid;   // 25*256 == 6400

            int win = -1;   // last valid box mapping to this cell wins
            #pragma unroll 4
            for (int n = 0; n < NBOX; n++) {
                const int cls = (int)gt[n * 5 + 0];
                const bool valid = (cls >= 0) && (cls < NUM_CLASSES) &&
                                   (gt[n * 5 + 3] > 0.0f) && (gt[n * 5 + 4] > 0.0f);
                if (valid) {
                    const float cx = fminf(fmaxf(gt[n * 5 + 1], 0.0f), 1.0f);
                    const float cy = fminf(fmaxf(gt[n * 5 + 2], 0.0f), 1.0f);
                    const int gx = min((int)(cx * (float)GRID_W), GRID_W - 1);
                    const int gy = min((int)(cy * (float)GRID_H), GRID_H - 1);
                    if (gy * GRID_W + gx == cell) win = n;
                }
            }
            const float* dl = det_logits + (size_t)b * 15 * NCELLS;
            const float x_obj = dl[4 * NCELLS + cell];
            const float tobj = (win >= 0) ? 1.0f : 0.0f;
            float obj;
            {
                const float e  = __expf(-fabsf(x_obj));
                const float sp = __builtin_amdgcn_rcpf(1.0f + e);
                const float sn = e * sp;
                obj = -__logf(((x_obj >= 0.0f) == (tobj > 0.5f)) ? sp : sn);
            }
            float boxl = 0.0f, clsl = 0.0f, posn = 0.0f;
            if (win >= 0) {
                posn = 1.0f;
                #pragma unroll
                for (int k = 0; k < 4; k++) {
                    const float xb = dl[k * NCELLS + cell];
                    const float e = __expf(-fabsf(xb));
                    const float sp = __builtin_amdgcn_rcpf(1.0f + e);
                    const float pb = (xb >= 0.0f) ? sp : e * sp;
                    const float tc = fminf(fmaxf(gt[win * 5 + 1 + k], 0.0f), 1.0f);
                    const float d = fabsf(pb - tc);
                    boxl += (d < 1.0f) ? 0.5f * d * d : d - 0.5f;
                }
                float lx[NUM_CLASSES];
                float mx = -INFINITY;
                #pragma unroll
                for (int c = 0; c < NUM_CLASSES; c++) {
                    lx[c] = dl[(5 + c) * NCELLS + cell];
                    mx = fmaxf(mx, lx[c]);
                }
                float se = 0.0f;
                #pragma unroll
                for (int c = 0; c < NUM_CLASSES; c++) se += __expf(lx[c] - mx);
                const int tcl = (int)gt[win * 5 + 0];
                clsl = -(lx[tcl] - mx - __logf(se));
            }
            reduce_atomic((double)obj,  &acc[0 + b],  smem);
            reduce_atomic((double)boxl, &acc[8 + b],  smem);
            reduce_atomic((double)clsl, &acc[16 + b], smem);
            reduce_atomic((double)posn, &acc[24 + b], smem);
        }
    } else if (y < 25) {
        // ---------------- RM channel ch = y-1
        const int ch = y - 1;
        const float4* lp = (const float4*)(rm_logits + (size_t)ch * SEG);
        const int4*   mp = (const int4*)(rm_mask   + (size_t)ch * SEG);
        const int stride = XBLK * TPB;          // threads per slice
        int p = blockIdx.x * TPB + tid;          // 32B-chunk index
        float focal = 0.f, inter = 0.f, ps = 0.f, ts = 0.f, cnt = 0.f;
        float4 a0 = lp[2 * p], a1 = lp[2 * p + 1];
        int4   b0 = mp[2 * p], b1 = mp[2 * p + 1];
        #pragma unroll
        for (int it = 0; it < 8; it++) {        // SEG/8 / stride == 8
            float4 na0, na1; int4 nb0, nb1;
            const int np_ = p + stride;
            if (it < 7) {
                na0 = lp[2 * np_]; na1 = lp[2 * np_ + 1];
                nb0 = mp[2 * np_]; nb1 = mp[2 * np_ + 1];
            }
            elem_rm(a0.x, b0.x, focal, inter, ps, ts, cnt);
            elem_rm(a0.y, b0.y, focal, inter, ps, ts, cnt);
            elem_rm(a0.z, b0.z, focal, inter, ps, ts, cnt);
            elem_rm(a0.w, b0.w, focal, inter, ps, ts, cnt);
            elem_rm(a1.x, b1.x, focal, inter, ps, ts, cnt);
            elem_rm(a1.y, b1.y, focal, inter, ps, ts, cnt);
            elem_rm(a1.z, b1.z, focal, inter, ps, ts, cnt);
            elem_rm(a1.w, b1.w, focal, inter, ps, ts, cnt);
            a0 = na0; a1 = na1; b0 = nb0; b1 = nb1;
            p = np_;
        }
        reduce_atomic((double)focal, &acc[48 + ch],  smem);
        reduce_atomic((double)inter, &acc[72 + ch],  smem);
        reduce_atomic((double)ps,    &acc[96 + ch],  smem);
        reduce_atomic((double)ts,    &acc[120 + ch], smem);
        reduce_atomic((double)cnt,   &acc[144 + ch], smem);
    } else {
        // ---------------- DA batch b = y-25
        const int b = y - 25;
        const float4* lp = (const float4*)(da_logits + (size_t)b * SEG);
        const int4*   mp = (const int4*)(da_mask   + (size_t)b * SEG);
        const int stride = XBLK * TPB;
        int p = blockIdx.x * TPB + tid;
        float s = 0.f, cnt = 0.f;
        float4 a0 = lp[2 * p], a1 = lp[2 * p + 1];
        int4   b0 = mp[2 * p], b1 = mp[2 * p + 1];
        #pragma unroll
        for (int it = 0; it < 8; it++) {
            float4 na0, na1; int4 nb0, nb1;
            const int np_ = p + stride;
            if (it < 7) {
                na0 = lp[2 * np_]; na1 = lp[2 * np_ + 1];
                nb0 = mp[2 * np_]; nb1 = mp[2 * np_ + 1];
            }
            elem_da(a0.x, b0.x, s, cnt);
            elem_da(a0.y, b0.y, s, cnt);
            elem_da(a0.z, b0.z, s, cnt);
            elem_da(a0.w, b0.w, s, cnt);
            elem_da(a1.x, b1.x, s, cnt);
            elem_da(a1.y, b1.y, s, cnt);
            elem_da(a1.z, b1.z, s, cnt);
            elem_da(a1.w, b1.w, s, cnt);
            a0 = na0; a1 = na1; b0 = nb0; b1 = nb1;
            p = np_;
        }
        reduce_atomic((double)s,   &acc[32 + b], smem);
        reduce_atomic((double)cnt, &acc[40 + b], smem);
    }
}

// ---------------- finalize ----------------
__global__ void final_kernel(const double* __restrict__ acc,
                             const int* __restrict__ has_det,
                             const int* __restrict__ has_da,
                             const int* __restrict__ has_rm,
                             float* __restrict__ out, int B) {
    if (threadIdx.x != 0 || blockIdx.x != 0) return;
    double od_num = 0.0, wsum = 0.0;
    for (int b = 0; b < B; b++) {
        const double np_ = fmax(acc[24 + b], 1.0);
        const double obj_b = acc[0 + b] / (double)NCELLS;
        const double box_b = acc[8 + b] / (np_ * 4.0);
        const double cls_b = acc[16 + b] / np_;
        const double w = (double)has_det[b];
        od_num += (obj_b + box_b + cls_b) * w;
        wsum += w;
    }
    const double od = od_num / fmax(wsum, 1.0);

    double da_num = 0.0, daw = 0.0;
    for (int b = 0; b < B; b++) {
        const double c = acc[40 + b];
        const double da_b = acc[32 + b] / fmax(c, 1.0);
        const double w = (double)has_da[b] * (c > 0.0 ? 1.0 : 0.0);
        da_num += da_b * w;
        daw += w;
    }
    const double da = da_num / fmax(daw, 1.0);

    double rm_num = 0.0, rmw = 0.0;
    for (int ch = 0; ch < 3 * B; ch++) {
        const double c = acc[144 + ch];
        const double focal = acc[48 + ch] / fmax(c, 1.0);
        const double dice = 1.0 - (2.0 * acc[72 + ch] + 1e-6) /
                                  (acc[96 + ch] + acc[120 + ch] + 1e-6);
        const double w = (double)has_rm[ch] * (c > 0.0 ? 1.0 : 0.0);
        rm_num += (focal + dice) * w;
        rmw += w;
    }
    const double rm = rm_num / fmax(rmw, 1.0);

    const double total = od + da + 2.0 * rm;
    out[0] = (float)total;
    out[1] = (float)od;
    out[2] = (float)da;
    out[3] = (float)rm;
}

extern "C" void kernel_launch(void* const* d_in, const int* in_sizes, int n_in,
                              void* d_out, int out_size, void* d_ws, size_t ws_size,
                              hipStream_t stream) {
    const float* det_logits = (const float*)d_in[0];
    const float* det_yolo   = (const float*)d_in[1];
    const float* da_logits  = (const float*)d_in[2];
    const int*   da_mask    = (const int*)d_in[3];
    const float* rm_logits  = (const float*)d_in[4];
    const int*   rm_mask    = (const int*)d_in[5];
    const int*   has_det    = (const int*)d_in[6];
    const int*   has_da     = (const int*)d_in[7];
    const int*   has_rm     = (const int*)d_in[8];
    float* out = (float*)d_out;
    double* acc = (double*)d_ws;

    const int B = in_sizes[6];   // 8

    hipMemsetAsync(acc, 0, WS_DOUBLES * sizeof(double), stream);

    fused_kernel<<<dim3(XBLK, 33), TPB, 0, stream>>>(
        det_logits, det_yolo, da_logits, da_mask, rm_logits, rm_mask, acc);
    final_kernel<<<1, 64, 0, stream>>>(acc, has_det, has_da, has_rm, out, B);
}

// Round 4
// 83.616 us; speedup vs baseline: 1.7498x; 1.7498x over previous
//
#include <hip/hip_runtime.h>
#include <math.h>

#define NUM_CLASSES 10
#define GRID_H 80
#define GRID_W 80
#define NCELLS (GRID_H * GRID_W)
#define NBOX 64
#define SEG (1024 * 1024)   // Hs*Ws per (batch[,channel])
#define XBLK 64
#define TPB 256

// ws layout (doubles):
//  0..7    obj_sum[b]
//  8..15   box_sum[b]
// 16..23   cls_sum[b]
// 24..31   npos[b]
// 32..39   da_sum[b]
// 40..47   da_cnt[b]
// 48..71   rm_focal[b*3+c]
// 72..95   rm_inter[ch]
// 96..119  rm_probsum[ch]
// 120..143 rm_rtsum[ch]
// 144..167 rm_cnt[ch]
#define WS_DOUBLES 168

__device__ __forceinline__ void reduce_atomic(double v, double* gdst, double* smem) {
    #pragma unroll
    for (int off = 32; off > 0; off >>= 1) v += __shfl_down(v, off, 64);
    int lane = threadIdx.x & 63, wid = threadIdx.x >> 6;
    __syncthreads();               // protect smem reuse across successive calls
    if (lane == 0) smem[wid] = v;
    __syncthreads();
    if (threadIdx.x == 0) {
        double s = 0.0;
        int nw = blockDim.x >> 6;
        for (int i = 0; i < nw; i++) s += smem[i];
        atomicAdd(gdst, s);
    }
}

// ---------------- streaming rm+da ----------------
// y in [0,24): rm channel y ; y in [24,32): da batch y-24
// Each thread owns 16 contiguous elements per grid-stride step:
// 4 float4 + 4 int4 independent loads in flight (64B/lane MLP).
__global__ __launch_bounds__(TPB, 8) void stream_kernel(
        const float* __restrict__ da_logits,
        const int*   __restrict__ da_mask,
        const float* __restrict__ rm_logits,
        const int*   __restrict__ rm_mask,
        double* __restrict__ acc) {
    __shared__ double smem[4];
    const int y = blockIdx.y;
    const bool is_rm = (y < 24);
    const float* lbase = is_rm ? rm_logits + (size_t)y * SEG
                               : da_logits + (size_t)(y - 24) * SEG;
    const int*   mbase = is_rm ? rm_mask + (size_t)y * SEG
                               : da_mask + (size_t)(y - 24) * SEG;

    float lsum = 0.f, inter = 0.f, ps = 0.f, ts = 0.f, cnt = 0.f;

    const int stride = XBLK * TPB * 16;               // 262144 elems
    for (int e = (blockIdx.x * TPB + threadIdx.x) * 16; e < SEG; e += stride) {
        const float4* lp = (const float4*)(lbase + e);
        const int4*   mp = (const int4*)(mbase + e);
        float4 a0 = lp[0], a1 = lp[1], a2 = lp[2], a3 = lp[3];
        int4   b0 = mp[0], b1 = mp[1], b2 = mp[2], b3 = mp[3];
        const float xs[16] = {a0.x,a0.y,a0.z,a0.w, a1.x,a1.y,a1.z,a1.w,
                              a2.x,a2.y,a2.z,a2.w, a3.x,a3.y,a3.z,a3.w};
        const int   ms[16] = {b0.x,b0.y,b0.z,b0.w, b1.x,b1.y,b1.z,b1.w,
                              b2.x,b2.y,b2.z,b2.w, b3.x,b3.y,b3.z,b3.w};
        #pragma unroll
        for (int k = 0; k < 16; k++) {
            const float x = xs[k];
            const int m = ms[k];
            const float vf = (m != 255) ? 1.0f : 0.0f;
            const float t  = (m != 255) ? (float)m : 0.0f;
            const float e_ = __expf(-fabsf(x));
            const float sp = __builtin_amdgcn_rcpf(1.0f + e_);
            const float sn = e_ * sp;
            const bool xp = (x >= 0.0f);
            const bool tp = (t > 0.5f);
            const float prob = xp ? sp : sn;          // sigmoid(x)
            const float pt   = (xp == tp) ? sp : sn;  // prob*t + (1-prob)*(1-t)
            const float om   = (xp == tp) ? sn : sp;  // 1 - pt
            const float bce  = -__logf(pt);
            const float fw   = is_rm ? om * om : 1.0f;  // focal weight (rm) or plain bce (da)
            lsum  += vf * fw * bce;
            inter += prob * t;                        // t==0 when invalid
            ps    += vf * prob;
            ts    += t;
            cnt   += vf;
        }
    }
    if (is_rm) {
        reduce_atomic((double)lsum,  &acc[48 + y],  smem);
        reduce_atomic((double)inter, &acc[72 + y],  smem);
        reduce_atomic((double)ps,    &acc[96 + y],  smem);
        reduce_atomic((double)ts,    &acc[120 + y], smem);
        reduce_atomic((double)cnt,   &acc[144 + y], smem);
    } else {
        reduce_atomic((double)lsum, &acc[32 + (y - 24)], smem);
        reduce_atomic((double)cnt,  &acc[40 + (y - 24)], smem);
    }
}

// ---------------- det (OD) ----------------
__global__ void det_kernel(const float* __restrict__ det_logits,
                           const float* __restrict__ det_yolo,
                           double* __restrict__ acc) {
    __shared__ float gt[NBOX * 5];
    __shared__ double smem[4];
    const int b = blockIdx.y;
    const int tid = threadIdx.x;
    const float* g = det_yolo + (size_t)b * NBOX * 5;
    for (int i = tid; i < NBOX * 5; i += blockDim.x) gt[i] = g[i];
    __syncthreads();

    const int cell = blockIdx.x * TPB + tid;   // 25 * 256 == 6400 exactly

    int win = -1;   // last valid box mapping to this cell wins
    #pragma unroll 4
    for (int n = 0; n < NBOX; n++) {
        const int cls = (int)gt[n * 5 + 0];
        const bool valid = (cls >= 0) && (cls < NUM_CLASSES) &&
                           (gt[n * 5 + 3] > 0.0f) && (gt[n * 5 + 4] > 0.0f);
        if (valid) {
            const float cx = fminf(fmaxf(gt[n * 5 + 1], 0.0f), 1.0f);
            const float cy = fminf(fmaxf(gt[n * 5 + 2], 0.0f), 1.0f);
            const int gx = min((int)(cx * (float)GRID_W), GRID_W - 1);
            const int gy = min((int)(cy * (float)GRID_H), GRID_H - 1);
            if (gy * GRID_W + gx == cell) win = n;
        }
    }
    const float* dl = det_logits + (size_t)b * 15 * NCELLS;
    const float x_obj = dl[4 * NCELLS + cell];
    const float tobj = (win >= 0) ? 1.0f : 0.0f;
    float obj;
    {
        const float e  = __expf(-fabsf(x_obj));
        const float sp = __builtin_amdgcn_rcpf(1.0f + e);
        const float sn = e * sp;
        obj = -__logf(((x_obj >= 0.0f) == (tobj > 0.5f)) ? sp : sn);
    }
    float boxl = 0.0f, clsl = 0.0f, posn = 0.0f;
    if (win >= 0) {
        posn = 1.0f;
        #pragma unroll
        for (int k = 0; k < 4; k++) {
            const float xb = dl[k * NCELLS + cell];
            const float e = __expf(-fabsf(xb));
            const float sp = __builtin_amdgcn_rcpf(1.0f + e);
            const float pb = (xb >= 0.0f) ? sp : e * sp;
            const float tc = fminf(fmaxf(gt[win * 5 + 1 + k], 0.0f), 1.0f);
            const float d = fabsf(pb - tc);
            boxl += (d < 1.0f) ? 0.5f * d * d : d - 0.5f;
        }
        float lx[NUM_CLASSES];
        float mx = -INFINITY;
        #pragma unroll
        for (int c = 0; c < NUM_CLASSES; c++) {
            lx[c] = dl[(5 + c) * NCELLS + cell];
            mx = fmaxf(mx, lx[c]);
        }
        float se = 0.0f;
        #pragma unroll
        for (int c = 0; c < NUM_CLASSES; c++) se += __expf(lx[c] - mx);
        const int tcl = (int)gt[win * 5 + 0];
        clsl = -(lx[tcl] - mx - __logf(se));
    }
    reduce_atomic((double)obj,  &acc[0 + b],  smem);
    reduce_atomic((double)boxl, &acc[8 + b],  smem);
    reduce_atomic((double)clsl, &acc[16 + b], smem);
    reduce_atomic((double)posn, &acc[24 + b], smem);
}

// ---------------- finalize ----------------
__global__ void final_kernel(const double* __restrict__ acc,
                             const int* __restrict__ has_det,
                             const int* __restrict__ has_da,
                             const int* __restrict__ has_rm,
                             float* __restrict__ out, int B) {
    if (threadIdx.x != 0 || blockIdx.x != 0) return;
    double od_num = 0.0, wsum = 0.0;
    for (int b = 0; b < B; b++) {
        const double np_ = fmax(acc[24 + b], 1.0);
        const double obj_b = acc[0 + b] / (double)NCELLS;
        const double box_b = acc[8 + b] / (np_ * 4.0);
        const double cls_b = acc[16 + b] / np_;
        const double w = (double)has_det[b];
        od_num += (obj_b + box_b + cls_b) * w;
        wsum += w;
    }
    const double od = od_num / fmax(wsum, 1.0);

    double da_num = 0.0, daw = 0.0;
    for (int b = 0; b < B; b++) {
        const double c = acc[40 + b];
        const double da_b = acc[32 + b] / fmax(c, 1.0);
        const double w = (double)has_da[b] * (c > 0.0 ? 1.0 : 0.0);
        da_num += da_b * w;
        daw += w;
    }
    const double da = da_num / fmax(daw, 1.0);

    double rm_num = 0.0, rmw = 0.0;
    for (int ch = 0; ch < 3 * B; ch++) {
        const double c = acc[144 + ch];
        const double focal = acc[48 + ch] / fmax(c, 1.0);
        const double dice = 1.0 - (2.0 * acc[72 + ch] + 1e-6) /
                                  (acc[96 + ch] + acc[120 + ch] + 1e-6);
        const double w = (double)has_rm[ch] * (c > 0.0 ? 1.0 : 0.0);
        rm_num += (focal + dice) * w;
        rmw += w;
    }
    const double rm = rm_num / fmax(rmw, 1.0);

    const double total = od + da + 2.0 * rm;
    out[0] = (float)total;
    out[1] = (float)od;
    out[2] = (float)da;
    out[3] = (float)rm;
}

extern "C" void kernel_launch(void* const* d_in, const int* in_sizes, int n_in,
                              void* d_out, int out_size, void* d_ws, size_t ws_size,
                              hipStream_t stream) {
    const float* det_logits = (const float*)d_in[0];
    const float* det_yolo   = (const float*)d_in[1];
    const float* da_logits  = (const float*)d_in[2];
    const int*   da_mask    = (const int*)d_in[3];
    const float* rm_logits  = (const float*)d_in[4];
    const int*   rm_mask    = (const int*)d_in[5];
    const int*   has_det    = (const int*)d_in[6];
    const int*   has_da     = (const int*)d_in[7];
    const int*   has_rm     = (const int*)d_in[8];
    float* out = (float*)d_out;
    double* acc = (double*)d_ws;

    const int B = in_sizes[6];   // 8

    hipMemsetAsync(acc, 0, WS_DOUBLES * sizeof(double), stream);

    det_kernel<<<dim3(NCELLS / TPB, B), TPB, 0, stream>>>(det_logits, det_yolo, acc);
    stream_kernel<<<dim3(XBLK, 32), TPB, 0, stream>>>(
        da_logits, da_mask, rm_logits, rm_mask, acc);
    final_kernel<<<1, 64, 0, stream>>>(acc, has_det, has_da, has_rm, out, B);
}